// Round 6
// baseline (1606.865 us; speedup 1.0000x reference)
//
#include <hip/hip_runtime.h>
#include <hip/hip_bf16.h>
#include <math.h>
#include <stdint.h>

#define NTOK 16384   // N = B*C
#define DH   1024    // D = H = EH = TH
#define NE   6       // experts
#define NT   3       // tasks
#define TAU  1e-4f   // near-tie rescue threshold on 3rd-vs-4th logit gap

typedef _Float16 f16x8 __attribute__((ext_vector_type(8)));
typedef float    f32x4 __attribute__((ext_vector_type(4)));

// ---------------------------------------------------------------------------
// global -> LDS staging, 16B per lane, wave-uniform base (lane*16 implicit)
// ---------------------------------------------------------------------------
__device__ __forceinline__ void stage16(const _Float16* g, _Float16* lds_base, int lane)
{
#if __has_builtin(__builtin_amdgcn_global_load_lds)
    __builtin_amdgcn_global_load_lds(
        (const __attribute__((address_space(1))) unsigned int*)(uintptr_t)g,
        (__attribute__((address_space(3))) unsigned int*)(uintptr_t)lds_base, 16, 0, 0);
#else
    *(float4*)(lds_base + lane * 8) = *(const float4*)g;
#endif
}

__device__ __forceinline__ f32x4 mfma16(f16x8 a, f16x8 b, f32x4 c)
{
    return __builtin_amdgcn_mfma_f32_16x16x32_f16(a, b, c, 0, 0, 0);
}

// ---------------------------------------------------------------------------
// fp16 MFMA 128x128 tile core. A [rows x DH] fp16, Bt [M x DH] fp16 (pre-T).
// 256 thr = 4 waves 2x2; wave = 64x64 via 4x4 of 16x16x32.
// ---------------------------------------------------------------------------
__device__ __forceinline__ void mfma_tile(const _Float16* __restrict__ A,
                                          const _Float16* __restrict__ Bt,
                                          int n0, int m0, f32x4 acc[4][4])
{
    __shared__ __align__(16) _Float16 As[128 * 32];
    __shared__ __align__(16) _Float16 Bs[128 * 32];
    const int tid  = threadIdx.x;
    const int w    = tid >> 6, lane = tid & 63;
    const int lr   = lane >> 2;
    const int lk   = (lane & 3) * 8;
    const int wm   = (w >> 1) * 64, wn = (w & 1) * 64;
    const int fl   = lane & 15;
    const int fq   = (lane >> 4) * 8;

    const _Float16* ga0 = A  + (size_t)(n0 + w * 32 + lr) * DH + lk;
    const _Float16* ga1 = ga0 + 16 * DH;
    const _Float16* gb0 = Bt + (size_t)(m0 + w * 32 + lr) * DH + lk;
    const _Float16* gb1 = gb0 + 16 * DH;
    _Float16* la0 = As + (w * 32) * 32;
    _Float16* la1 = la0 + 16 * 32;
    _Float16* lb0 = Bs + (w * 32) * 32;
    _Float16* lb1 = lb0 + 16 * 32;

    for (int ks = 0; ks < DH; ks += 32) {
        __syncthreads();
        stage16(ga0 + ks, la0, lane);
        stage16(ga1 + ks, la1, lane);
        stage16(gb0 + ks, lb0, lane);
        stage16(gb1 + ks, lb1, lane);
        __syncthreads();
        f16x8 af[4], bf[4];
#pragma unroll
        for (int i = 0; i < 4; ++i)
            af[i] = *(const f16x8*)(As + (wm + i * 16 + fl) * 32 + fq);
#pragma unroll
        for (int j = 0; j < 4; ++j)
            bf[j] = *(const f16x8*)(Bs + (wn + j * 16 + fl) * 32 + fq);
#pragma unroll
        for (int i = 0; i < 4; ++i)
#pragma unroll
            for (int j = 0; j < 4; ++j)
                acc[i][j] = mfma16(af[i], bf[j], acc[i][j]);
    }
}

// ---------------------------------------------------------------------------
// Split-fp16 (hi+lo) MFMA tile: acc += Ahi*Bhi + Ahi*Blo + Alo*Bhi.
// fp32-accuracy GEMM at MFMA rate (err ~2^-22 rel; np fp32 ref is ~2^-21).
// ---------------------------------------------------------------------------
__device__ __forceinline__ void mfma_tile_split(const _Float16* __restrict__ Ah,
                                                const _Float16* __restrict__ Al,
                                                const _Float16* __restrict__ Bh,
                                                const _Float16* __restrict__ Bl,
                                                int n0, int m0, f32x4 acc[4][4])
{
    __shared__ __align__(16) _Float16 Ash[128 * 32];
    __shared__ __align__(16) _Float16 Asl[128 * 32];
    __shared__ __align__(16) _Float16 Bsh[128 * 32];
    __shared__ __align__(16) _Float16 Bsl[128 * 32];
    const int tid  = threadIdx.x;
    const int w    = tid >> 6, lane = tid & 63;
    const int lr   = lane >> 2;
    const int lk   = (lane & 3) * 8;
    const int wm   = (w >> 1) * 64, wn = (w & 1) * 64;
    const int fl   = lane & 15;
    const int fq   = (lane >> 4) * 8;

    const size_t ro = (size_t)(n0 + w * 32 + lr) * DH + lk;
    const size_t co = (size_t)(m0 + w * 32 + lr) * DH + lk;
    const int lo0 = (w * 32) * 32, lo1 = lo0 + 16 * 32;

    for (int ks = 0; ks < DH; ks += 32) {
        __syncthreads();
        stage16(Ah + ro + ks,            Ash + lo0, lane);
        stage16(Ah + ro + 16 * DH + ks,  Ash + lo1, lane);
        stage16(Al + ro + ks,            Asl + lo0, lane);
        stage16(Al + ro + 16 * DH + ks,  Asl + lo1, lane);
        stage16(Bh + co + ks,            Bsh + lo0, lane);
        stage16(Bh + co + 16 * DH + ks,  Bsh + lo1, lane);
        stage16(Bl + co + ks,            Bsl + lo0, lane);
        stage16(Bl + co + 16 * DH + ks,  Bsl + lo1, lane);
        __syncthreads();
        f16x8 ah[4], al[4], bh[4], bl[4];
#pragma unroll
        for (int i = 0; i < 4; ++i) {
            const int off = (wm + i * 16 + fl) * 32 + fq;
            ah[i] = *(const f16x8*)(Ash + off);
            al[i] = *(const f16x8*)(Asl + off);
        }
#pragma unroll
        for (int j = 0; j < 4; ++j) {
            const int off = (wn + j * 16 + fl) * 32 + fq;
            bh[j] = *(const f16x8*)(Bsh + off);
            bl[j] = *(const f16x8*)(Bsl + off);
        }
#pragma unroll
        for (int i = 0; i < 4; ++i)
#pragma unroll
            for (int j = 0; j < 4; ++j) {
                acc[i][j] = mfma16(al[i], bh[j], acc[i][j]);
                acc[i][j] = mfma16(ah[i], bl[j], acc[i][j]);
                acc[i][j] = mfma16(ah[i], bh[j], acc[i][j]);
            }
    }
}

// C/D layout: col = wn + j*16 + (lane&15); row = wm + i*16 + (lane>>4)*4 + reg.

// ---------------------------------------------------------------------------
// fc1: h1 = relu(x@w1 + b1), output as split fp16 pair (hi, lo)
// ---------------------------------------------------------------------------
__global__ __launch_bounds__(256) void k_fc1(const _Float16* __restrict__ xh,
                                             const _Float16* __restrict__ xl,
                                             const _Float16* __restrict__ wh,
                                             const _Float16* __restrict__ wl,
                                             const float* __restrict__ bias,
                                             _Float16* __restrict__ oh,
                                             _Float16* __restrict__ ol)
{
    f32x4 acc[4][4] = {};
    const int n0 = blockIdx.x * 128, m0 = blockIdx.y * 128;
    mfma_tile_split(xh, xl, wh, wl, n0, m0, acc);
    const int lane = threadIdx.x & 63, w = threadIdx.x >> 6;
    const int wm = (w >> 1) * 64, wn = (w & 1) * 64;
    const int fl = lane & 15, quad = lane >> 4;
#pragma unroll
    for (int i = 0; i < 4; ++i)
#pragma unroll
        for (int reg = 0; reg < 4; ++reg) {
            const int r = n0 + wm + i * 16 + quad * 4 + reg;
#pragma unroll
            for (int j = 0; j < 4; ++j) {
                const int c = m0 + wn + j * 16 + fl;
                const float v = fmaxf(acc[i][j][reg] + bias[c], 0.0f);
                const _Float16 h = (_Float16)v;
                oh[(size_t)r * DH + c] = h;
                ol[(size_t)r * DH + c] = (_Float16)(v - (float)h);
            }
        }
}

// ---------------------------------------------------------------------------
// fc2: h = h1@w2 + b2 -> h32 (fp64 rescue), h16 hi (experts+logits), h16l lo
// ---------------------------------------------------------------------------
__global__ __launch_bounds__(256) void k_fc2(const _Float16* __restrict__ ah,
                                             const _Float16* __restrict__ al,
                                             const _Float16* __restrict__ wh,
                                             const _Float16* __restrict__ wl,
                                             const float* __restrict__ bias,
                                             float* __restrict__ h32,
                                             _Float16* __restrict__ h16,
                                             _Float16* __restrict__ h16l)
{
    f32x4 acc[4][4] = {};
    const int n0 = blockIdx.x * 128, m0 = blockIdx.y * 128;
    mfma_tile_split(ah, al, wh, wl, n0, m0, acc);
    const int lane = threadIdx.x & 63, w = threadIdx.x >> 6;
    const int wm = (w >> 1) * 64, wn = (w & 1) * 64;
    const int fl = lane & 15, quad = lane >> 4;
#pragma unroll
    for (int i = 0; i < 4; ++i)
#pragma unroll
        for (int reg = 0; reg < 4; ++reg) {
            const int r = n0 + wm + i * 16 + quad * 4 + reg;
#pragma unroll
            for (int j = 0; j < 4; ++j) {
                const int c = m0 + wn + j * 16 + fl;
                const float v = acc[i][j][reg] + bias[c];
                const _Float16 h = (_Float16)v;
                h32[(size_t)r * DH + c] = v;
                h16[(size_t)r * DH + c] = h;
                h16l[(size_t)r * DH + c] = (_Float16)(v - (float)h);
            }
        }
}

// ---------------------------------------------------------------------------
// Gating logits via split-fp16 MFMA: logits[c][n] = h[n,:].wg[:,c], c=t*6+e
// (32 cols, 18 real + zero pad). Block = 128 thr = 2 waves, 64 tokens.
// ---------------------------------------------------------------------------
__global__ __launch_bounds__(128) void k_logits(const _Float16* __restrict__ hh,
                                                const _Float16* __restrict__ hl,
                                                const _Float16* __restrict__ wgh, // [32][DH]
                                                const _Float16* __restrict__ wgl,
                                                float* __restrict__ logits,       // [32][chunk]
                                                int chunk)
{
    __shared__ __align__(16) _Float16 Ash[64 * 32];
    __shared__ __align__(16) _Float16 Asl[64 * 32];
    __shared__ __align__(16) _Float16 Bsh[32 * 32];
    __shared__ __align__(16) _Float16 Bsl[32 * 32];
    const int tid = threadIdx.x;
    const int w = tid >> 6, lane = tid & 63;
    const int lr = lane >> 2, lk = (lane & 3) * 8;
    const int fl = lane & 15, fq = (lane >> 4) * 8;
    const int n0 = blockIdx.x * 64;

    const size_t ro = (size_t)(n0 + w * 32 + lr) * DH + lk;
    const size_t bo = (size_t)lr * DH + lk;
    const int la0 = (w * 32) * 32, la1 = la0 + 16 * 32;

    f32x4 acc[2][2] = {};
    for (int ks = 0; ks < DH; ks += 32) {
        __syncthreads();
        stage16(hh + ro + ks,           Ash + la0, lane);
        stage16(hh + ro + 16 * DH + ks, Ash + la1, lane);
        stage16(hl + ro + ks,           Asl + la0, lane);
        stage16(hl + ro + 16 * DH + ks, Asl + la1, lane);
        if (w == 0) {
            stage16(wgh + bo + ks,           Bsh,           lane);
            stage16(wgh + bo + 16 * DH + ks, Bsh + 16 * 32, lane);
        } else {
            stage16(wgl + bo + ks,           Bsl,           lane);
            stage16(wgl + bo + 16 * DH + ks, Bsl + 16 * 32, lane);
        }
        __syncthreads();
        f16x8 ah[2], al[2], bh[2], bl[2];
#pragma unroll
        for (int i = 0; i < 2; ++i) {
            const int off = (w * 32 + i * 16 + fl) * 32 + fq;
            ah[i] = *(const f16x8*)(Ash + off);
            al[i] = *(const f16x8*)(Asl + off);
        }
#pragma unroll
        for (int j = 0; j < 2; ++j) {
            const int off = (j * 16 + fl) * 32 + fq;
            bh[j] = *(const f16x8*)(Bsh + off);
            bl[j] = *(const f16x8*)(Bsl + off);
        }
#pragma unroll
        for (int i = 0; i < 2; ++i)
#pragma unroll
            for (int j = 0; j < 2; ++j) {
                acc[i][j] = mfma16(al[i], bh[j], acc[i][j]);
                acc[i][j] = mfma16(ah[i], bl[j], acc[i][j]);
                acc[i][j] = mfma16(ah[i], bh[j], acc[i][j]);
            }
    }
    const int quad = lane >> 4;
#pragma unroll
    for (int i = 0; i < 2; ++i)
#pragma unroll
        for (int reg = 0; reg < 4; ++reg) {
            const int r = n0 + w * 32 + i * 16 + quad * 4 + reg;
#pragma unroll
            for (int j = 0; j < 2; ++j) {
                const int c = j * 16 + fl;
                logits[(size_t)c * chunk + r] = acc[i][j][reg];
            }
        }
}

// ---------------------------------------------------------------------------
// Select: per-token top-3 + fp32 softmax -> gates; flag near-ties (3rd vs 4th)
// ---------------------------------------------------------------------------
__global__ __launch_bounds__(256) void k_select(const float* __restrict__ logits, // [32][chunk]
                                                float* __restrict__ gates,        // [E][T][chunk]
                                                unsigned char* __restrict__ flags,
                                                int chunk)
{
    const int n = blockIdx.x * 256 + threadIdx.x;
    if (n >= chunk) return;
    float l[18];
#pragma unroll
    for (int c = 0; c < 18; ++c) l[c] = logits[(size_t)c * chunk + n];
    unsigned char f = 0;
#pragma unroll
    for (int t = 0; t < NT; ++t) {
        float a[NE];
#pragma unroll
        for (int e = 0; e < NE; ++e) a[e] = l[t * NE + e];
        bool used[NE] = {false, false, false, false, false, false};
        int idx[3];
        float tv[3];
#pragma unroll
        for (int k = 0; k < 3; ++k) {
            int best = -1;
#pragma unroll
            for (int e = 0; e < NE; ++e)
                if (!used[e] && (best < 0 || a[e] > a[best])) best = e;
            used[best] = true;
            idx[k] = best;
            tv[k] = a[best];
        }
        float v4 = -3.4e38f;
#pragma unroll
        for (int e = 0; e < NE; ++e)
            if (!used[e] && a[e] > v4) v4 = a[e];
        if (tv[2] - v4 < TAU) f = 1;
        const float m = tv[0];
        const float w0 = expf(tv[0] - m), w1 = expf(tv[1] - m), w2 = expf(tv[2] - m);
        const float s = w0 + w1 + w2;
        float g[NE] = {0.f, 0.f, 0.f, 0.f, 0.f, 0.f};
        g[idx[0]] = w0 / s;
        g[idx[1]] = w1 / s;
        g[idx[2]] = w2 / s;
#pragma unroll
        for (int e = 0; e < NE; ++e)
            gates[(size_t)(e * NT + t) * chunk + n] = g[e];
    }
    flags[n] = f;
}

// ---------------------------------------------------------------------------
// Rescue: fp64-exact gating for flagged (near-tie) tokens only. Wave-per-token.
// ---------------------------------------------------------------------------
__global__ __launch_bounds__(256) void k_rescue(const float* __restrict__ h,    // [chunk][DH]
                                                const double* __restrict__ wgt, // [T][E][DH]
                                                const unsigned char* __restrict__ flags,
                                                float* __restrict__ gates,      // [E][T][chunk]
                                                int chunk)
{
    const int w = threadIdx.x >> 6, lane = threadIdx.x & 63;
    const int n = blockIdx.x * 4 + w;
    if (!flags[n]) return;   // wave-uniform early out

    double acc[NT][NE] = {};
#pragma unroll 4
    for (int i = 0; i < 16; ++i) {
        const int k = lane + 64 * i;
        const double hv = (double)h[(size_t)n * DH + k];
#pragma unroll
        for (int t = 0; t < NT; ++t)
#pragma unroll
            for (int e = 0; e < NE; ++e)
                acc[t][e] += hv * wgt[(size_t)(t * NE + e) * DH + k];
    }
#pragma unroll
    for (int d = 1; d < 64; d <<= 1)
#pragma unroll
        for (int t = 0; t < NT; ++t)
#pragma unroll
            for (int e = 0; e < NE; ++e)
                acc[t][e] += __shfl_xor(acc[t][e], d, 64);

    if (lane < NT) {
        const int t = lane;
        double a[NE];
#pragma unroll
        for (int e = 0; e < NE; ++e) a[e] = acc[t][e];
        bool used[NE] = {false, false, false, false, false, false};
        int idx[3];
        double tv[3];
#pragma unroll
        for (int k = 0; k < 3; ++k) {
            int best = -1;
#pragma unroll
            for (int e = 0; e < NE; ++e)
                if (!used[e] && (best < 0 || a[e] > a[best])) best = e;
            used[best] = true;
            idx[k] = best;
            tv[k] = a[best];
        }
        const double m  = tv[0];
        const double w0 = exp(tv[0] - m), w1 = exp(tv[1] - m), w2 = exp(tv[2] - m);
        const double sum = w0 + w1 + w2;
        float g[NE] = {0.f, 0.f, 0.f, 0.f, 0.f, 0.f};
        g[idx[0]] = (float)(w0 / sum);
        g[idx[1]] = (float)(w1 / sum);
        g[idx[2]] = (float)(w2 / sum);
#pragma unroll
        for (int e = 0; e < NE; ++e)
            gates[(size_t)(e * NT + t) * chunk + n] = g[e];
    }
}

// ---------------------------------------------------------------------------
// Expert layer 1, all experts (z = e): eh[e] = fp16(relu(h16 @ ew1t[e]^T + eb1[e]))
// ---------------------------------------------------------------------------
__global__ __launch_bounds__(256) void k_expert1(const _Float16* __restrict__ A,
                                                 const _Float16* __restrict__ ew1t,
                                                 const float* __restrict__ eb1,
                                                 _Float16* __restrict__ eh,
                                                 int chunk)
{
    const int e = blockIdx.z;
    const _Float16* Bt = ew1t + (size_t)e * DH * DH;
    const float* bias  = eb1 + e * DH;
    _Float16* C        = eh + (size_t)e * chunk * DH;

    f32x4 acc[4][4] = {};
    const int n0 = blockIdx.x * 128, m0 = blockIdx.y * 128;
    mfma_tile(A, Bt, n0, m0, acc);
    const int lane = threadIdx.x & 63, w = threadIdx.x >> 6;
    const int wm = (w >> 1) * 64, wn = (w & 1) * 64;
    const int fl = lane & 15, quad = lane >> 4;
#pragma unroll
    for (int i = 0; i < 4; ++i)
#pragma unroll
        for (int reg = 0; reg < 4; ++reg) {
            const int r = n0 + wm + i * 16 + quad * 4 + reg;
#pragma unroll
            for (int j = 0; j < 4; ++j) {
                const int c = m0 + wn + j * 16 + fl;
                C[(size_t)r * DH + c] = (_Float16)fmaxf(acc[i][j][reg] + bias[c], 0.0f);
            }
        }
}

// ---------------------------------------------------------------------------
// Expert layer 2, all experts (z = e): eo[e] = fp16(eh[e] @ ew2t[e]^T + eb2[e])
// ---------------------------------------------------------------------------
__global__ __launch_bounds__(256) void k_expert2(const _Float16* __restrict__ eh,
                                                 const _Float16* __restrict__ ew2t,
                                                 const float* __restrict__ eb2,
                                                 _Float16* __restrict__ eo,
                                                 int chunk)
{
    const int e = blockIdx.z;
    const _Float16* A  = eh + (size_t)e * chunk * DH;
    const _Float16* Bt = ew2t + (size_t)e * DH * DH;
    const float* bias  = eb2 + e * DH;
    _Float16* C        = eo + (size_t)e * chunk * DH;

    f32x4 acc[4][4] = {};
    const int n0 = blockIdx.x * 128, m0 = blockIdx.y * 128;
    mfma_tile(A, Bt, n0, m0, acc);
    const int lane = threadIdx.x & 63, w = threadIdx.x >> 6;
    const int wm = (w >> 1) * 64, wn = (w & 1) * 64;
    const int fl = lane & 15, quad = lane >> 4;
#pragma unroll
    for (int i = 0; i < 4; ++i)
#pragma unroll
        for (int reg = 0; reg < 4; ++reg) {
            const int r = n0 + wm + i * 16 + quad * 4 + reg;
#pragma unroll
            for (int j = 0; j < 4; ++j) {
                const int c = m0 + wn + j * 16 + fl;
                C[(size_t)r * DH + c] = (_Float16)(acc[i][j][reg] + bias[c]);
            }
        }
}

// ---------------------------------------------------------------------------
// Gated combine: mo[t][n][:] = sum_e gates[e][t][n] * eo[e][n][:]
// ---------------------------------------------------------------------------
__global__ __launch_bounds__(256) void k_combine(const _Float16* __restrict__ eo,
                                                 const float* __restrict__ gates, // [E][T][chunk]
                                                 _Float16* __restrict__ mo,       // [T][chunk][DH]
                                                 int chunk)
{
    const size_t plane = (size_t)chunk * DH;
    const size_t idx = (size_t)blockIdx.x * 256 + threadIdx.x;
    const size_t off = idx * 8;
    if (off >= plane) return;
    const int n = (int)(off / DH);

    float acc[NT][8] = {};
#pragma unroll
    for (int e = 0; e < NE; ++e) {
        const f16x8 v = *(const f16x8*)(eo + e * plane + off);
        float vf[8];
#pragma unroll
        for (int j = 0; j < 8; ++j) vf[j] = (float)v[j];
#pragma unroll
        for (int t = 0; t < NT; ++t) {
            const float g = gates[(size_t)(e * NT + t) * chunk + n];
#pragma unroll
            for (int j = 0; j < 8; ++j) acc[t][j] += g * vf[j];
        }
    }
#pragma unroll
    for (int t = 0; t < NT; ++t) {
        f16x8 r;
#pragma unroll
        for (int j = 0; j < 8; ++j) r[j] = (_Float16)acc[t][j];
        *(f16x8*)(mo + t * plane + off) = r;
    }
}

// ---------------------------------------------------------------------------
// Tower: th = relu(mo[t]@tw1t[t]^T + tb1[t]); out[t][n] += th . tw2[t]
// ---------------------------------------------------------------------------
__global__ __launch_bounds__(256) void k_mfma_tower(const _Float16* __restrict__ mo,
                                                    const _Float16* __restrict__ tw1t,
                                                    const float* __restrict__ tb1,
                                                    const float* __restrict__ tw2,
                                                    float* __restrict__ out,
                                                    int n_base, int chunk)
{
    const int t = blockIdx.z;
    const _Float16* A  = mo   + (size_t)t * chunk * DH;
    const _Float16* Bt = tw1t + (size_t)t * DH * DH;
    const float* b1 = tb1 + t * DH;
    const float* w2 = tw2 + t * DH;

    f32x4 acc[4][4] = {};
    const int n0 = blockIdx.x * 128, m0 = blockIdx.y * 128;
    mfma_tile(A, Bt, n0, m0, acc);
    const int lane = threadIdx.x & 63, w = threadIdx.x >> 6;
    const int wm = (w >> 1) * 64, wn = (w & 1) * 64;
    const int fl = lane & 15, quad = lane >> 4;

    float s[4][4];
#pragma unroll
    for (int i = 0; i < 4; ++i)
#pragma unroll
        for (int reg = 0; reg < 4; ++reg) {
            float v = 0.0f;
#pragma unroll
            for (int j = 0; j < 4; ++j) {
                const int c = m0 + wn + j * 16 + fl;
                v += fmaxf(acc[i][j][reg] + b1[c], 0.0f) * w2[c];
            }
            s[i][reg] = v;
        }
#pragma unroll
    for (int d = 8; d > 0; d >>= 1)
#pragma unroll
        for (int i = 0; i < 4; ++i)
#pragma unroll
            for (int reg = 0; reg < 4; ++reg)
                s[i][reg] += __shfl_down(s[i][reg], d, 16);
    if (fl == 0) {
#pragma unroll
        for (int i = 0; i < 4; ++i)
#pragma unroll
            for (int reg = 0; reg < 4; ++reg) {
                const int r = n0 + wm + i * 16 + quad * 4 + reg;
                atomicAdd(out + (size_t)t * NTOK + n_base + r, s[i][reg]);
            }
    }
}

// ---------------------------------------------------------------------------
// Utility kernels
// ---------------------------------------------------------------------------
__global__ __launch_bounds__(256) void k_init_out(float* __restrict__ out,
                                                  const float* __restrict__ tb2)
{
    const int i = blockIdx.x * 256 + threadIdx.x;
    if (i < NT * NTOK) out[i] = tb2[i >> 14];
}

// vectorized split fp32 -> (hi, lo) fp16, 8 elems/thread
__global__ __launch_bounds__(256) void k_xsplit8(const float* __restrict__ s,
                                                 _Float16* __restrict__ hi,
                                                 _Float16* __restrict__ lo, size_t n8)
{
    const size_t i = (size_t)blockIdx.x * 256 + threadIdx.x;
    if (i >= n8) return;
    const size_t off = i * 8;
    const float4 a = *(const float4*)(s + off);
    const float4 b = *(const float4*)(s + off + 4);
    const float v[8] = {a.x, a.y, a.z, a.w, b.x, b.y, b.z, b.w};
    f16x8 H, L;
#pragma unroll
    for (int j = 0; j < 8; ++j) {
        const _Float16 h = (_Float16)v[j];
        H[j] = h;
        L[j] = (_Float16)(v[j] - (float)h);
    }
    *(f16x8*)(hi + off) = H;
    *(f16x8*)(lo + off) = L;
}

// transpose one DH x DH fp32 [K][M] -> fp16 [M][K]; matrix index blockIdx.z
__global__ __launch_bounds__(256) void k_w16t(const float* __restrict__ src,
                                              _Float16* __restrict__ dst)
{
    __shared__ float t[32][33];
    const float* s = src + (size_t)blockIdx.z * DH * DH;
    _Float16* d    = dst + (size_t)blockIdx.z * DH * DH;
    const int k0 = blockIdx.x * 32, m0 = blockIdx.y * 32;
    const int tx = threadIdx.x & 31, ty = threadIdx.x >> 5;
    for (int r = ty; r < 32; r += 8)
        t[r][tx] = s[(size_t)(k0 + r) * DH + m0 + tx];
    __syncthreads();
    for (int r = ty; r < 32; r += 8)
        d[(size_t)(m0 + r) * DH + k0 + tx] = (_Float16)t[tx][r];
}

// transpose + split one DH x DH fp32 [K][M] -> fp16 hi/lo [M][K]
__global__ __launch_bounds__(256) void k_wsplit_t(const float* __restrict__ src,
                                                  _Float16* __restrict__ dhi,
                                                  _Float16* __restrict__ dlo)
{
    __shared__ float t[32][33];
    const int k0 = blockIdx.x * 32, m0 = blockIdx.y * 32;
    const int tx = threadIdx.x & 31, ty = threadIdx.x >> 5;
    for (int r = ty; r < 32; r += 8)
        t[r][tx] = src[(size_t)(k0 + r) * DH + m0 + tx];
    __syncthreads();
    for (int r = ty; r < 32; r += 8) {
        const float v = t[tx][r];
        const _Float16 h = (_Float16)v;
        dhi[(size_t)(m0 + r) * DH + k0 + tx] = h;
        dlo[(size_t)(m0 + r) * DH + k0 + tx] = (_Float16)(v - (float)h);
    }
}

// w_gate [T][DH][E] fp32 -> wgt [T][E][DH] fp64 (rescue path)
__global__ __launch_bounds__(256) void k_wg_t(const float* __restrict__ wg,
                                              double* __restrict__ wgt)
{
    const int i = blockIdx.x * 256 + threadIdx.x;
    if (i < NT * NE * DH) {
        const int k = i & (DH - 1);
        const int te = i >> 10;
        const int e = te % NE, t = te / NE;
        wgt[i] = (double)wg[((size_t)t * DH + k) * NE + e];
    }
}

// w_gate [T][DH][E] fp32 -> split fp16 [32][DH] (c = t*6+e, rows 18..31 zero)
__global__ __launch_bounds__(256) void k_wgsplit(const float* __restrict__ wg,
                                                 _Float16* __restrict__ wgh,
                                                 _Float16* __restrict__ wgl)
{
    const int i = blockIdx.x * 256 + threadIdx.x;
    if (i >= 32 * DH) return;
    const int k = i & (DH - 1);
    const int c = i >> 10;
    float v = 0.0f;
    if (c < NT * NE) {
        const int t = c / NE, e = c - t * NE;
        v = wg[((size_t)t * DH + k) * NE + e];
    }
    const _Float16 h = (_Float16)v;
    wgh[i] = h;
    wgl[i] = (_Float16)(v - (float)h);
}

// ---------------------------------------------------------------------------
extern "C" void kernel_launch(void* const* d_in, const int* in_sizes, int n_in,
                              void* d_out, int out_size, void* d_ws, size_t ws_size,
                              hipStream_t stream)
{
    const float* x      = (const float*)d_in[0];
    const float* fc1_w  = (const float*)d_in[1];
    const float* fc1_b  = (const float*)d_in[2];
    const float* fc2_w  = (const float*)d_in[3];
    const float* fc2_b  = (const float*)d_in[4];
    const float* w_gate = (const float*)d_in[5];
    const float* ew1    = (const float*)d_in[6];
    const float* eb1    = (const float*)d_in[7];
    const float* ew2    = (const float*)d_in[8];
    const float* eb2    = (const float*)d_in[9];
    const float* tw1    = (const float*)d_in[10];
    const float* tb1    = (const float*)d_in[11];
    const float* tw2    = (const float*)d_in[12];
    const float* tb2    = (const float*)d_in[13];
    float* out = (float*)d_out;

    const size_t plane = (size_t)DH * DH * 2;           // 2 MiB
    // fixed: 19 fp16 weight planes + wgt fp64 + wgh/wgl fp16
    const size_t fixed = 19 * plane + (size_t)NT * NE * DH * 8 + (size_t)2 * 32 * DH * 2;
    // per-token: eh(6) + h16 + h16l + eo(6) fp16 planes + gates + flags
    const size_t per_tok = (size_t)14 * DH * 2 + NE * NT * 4 + 1;
    int chunk = 16384;
    while (chunk > 128 && fixed + (size_t)chunk * per_tok > ws_size) chunk >>= 1;

    char* p = (char*)d_ws;
    _Float16* ew1t = (_Float16*)p; p += NE * plane;
    _Float16* ew2t = (_Float16*)p; p += NE * plane;
    _Float16* tw1t = (_Float16*)p; p += NT * plane;
    _Float16* w1th = (_Float16*)p; p += plane;
    _Float16* w1tl = (_Float16*)p; p += plane;
    _Float16* w2th = (_Float16*)p; p += plane;
    _Float16* w2tl = (_Float16*)p; p += plane;
    double* wgt    = (double*)p;   p += (size_t)NT * NE * DH * 8;
    _Float16* wgh  = (_Float16*)p; p += (size_t)32 * DH * 2;
    _Float16* wgl  = (_Float16*)p; p += (size_t)32 * DH * 2;

    const size_t cpe = (size_t)chunk * DH;     // chunk-plane elements
    _Float16* eh   = (_Float16*)p; p += 6 * cpe * 2;
    _Float16* h16  = (_Float16*)p; p += cpe * 2;
    _Float16* h16l = (_Float16*)p; p += cpe * 2;
    _Float16* eo   = (_Float16*)p; p += 6 * cpe * 2;
    float* gates   = (float*)p;    p += (size_t)NE * NT * chunk * 4;
    unsigned char* flags = (unsigned char*)p; p += chunk;

    // aliases inside eh (lifetimes end before eh is written by k_expert1)
    _Float16* xh  = eh + 0 * cpe;
    _Float16* xl  = eh + 1 * cpe;
    _Float16* h1h = eh + 2 * cpe;
    _Float16* h1l = eh + 3 * cpe;
    float*    h32 = (float*)(eh + 4 * cpe);    // planes 4-5
    _Float16* mo  = eh;                        // 3 planes, after eh dead
    float* logits = (float*)eo;                // 32*chunk*4 B, dead before expert2

    const dim3 blk(256);
    const dim3 gm(chunk / 128, DH / 128);
    const dim3 gme(chunk / 128, DH / 128, NE);

    k_init_out<<<dim3((NT * NTOK + 255) / 256), blk, 0, stream>>>(out, tb2);

    // one-time weight prep
    k_w16t<<<dim3(32, 32, NE), blk, 0, stream>>>(ew1, ew1t);
    k_w16t<<<dim3(32, 32, NE), blk, 0, stream>>>(ew2, ew2t);
    k_w16t<<<dim3(32, 32, NT), blk, 0, stream>>>(tw1, tw1t);
    k_wsplit_t<<<dim3(32, 32), blk, 0, stream>>>(fc1_w, w1th, w1tl);
    k_wsplit_t<<<dim3(32, 32), blk, 0, stream>>>(fc2_w, w2th, w2tl);
    k_wg_t<<<dim3((NT * NE * DH + 255) / 256), blk, 0, stream>>>(w_gate, wgt);
    k_wgsplit<<<dim3((32 * DH + 255) / 256), blk, 0, stream>>>(w_gate, wgh, wgl);

    for (int nb = 0; nb < NTOK; nb += chunk) {
        const float* xc = x + (size_t)nb * DH;

        // shared bottom via split-fp16 MFMA (fp32-accurate -> selection-safe)
        k_xsplit8<<<dim3((unsigned)((cpe / 8 + 255) / 256)), blk, 0, stream>>>(xc, xh, xl, cpe / 8);
        k_fc1<<<gm, blk, 0, stream>>>(xh, xl, w1th, w1tl, fc1_b, h1h, h1l);
        k_fc2<<<gm, blk, 0, stream>>>(h1h, h1l, w2th, w2tl, fc2_b, h32, h16, h16l);

        // gating: MFMA logits + fp32 select + fp64 rescue of near-ties
        k_logits<<<dim3(chunk / 64), dim3(128), 0, stream>>>(h16, h16l, wgh, wgl, logits, chunk);
        k_select<<<dim3(chunk / 256), blk, 0, stream>>>(logits, gates, flags, chunk);
        k_rescue<<<dim3(chunk / 4), blk, 0, stream>>>(h32, wgt, flags, gates, chunk);

        // experts: both layers fully parallel over e
        k_expert1<<<gme, blk, 0, stream>>>(h16, ew1t, eb1, eh, chunk);
        k_expert2<<<gme, blk, 0, stream>>>(eh, ew2t, eb2, eo, chunk);

        // gated combine (elementwise) -> mo (reuses eh planes 0-2)
        k_combine<<<dim3((unsigned)((cpe / 8 + 255) / 256)), blk, 0, stream>>>(
            eo, gates, mo, chunk);

        // towers via fp16 MFMA + fused final dot
        k_mfma_tower<<<dim3(chunk / 128, DH / 128, NT), blk, 0, stream>>>(
            mo, tw1t, tb1, tw2, out, nb, chunk);
    }
}

// Round 7
// 1307.030 us; speedup vs baseline: 1.2294x; 1.2294x over previous
//
#include <hip/hip_runtime.h>
#include <hip/hip_bf16.h>
#include <math.h>
#include <stdint.h>

#define NTOK 16384   // N = B*C
#define DH   1024    // D = H = EH = TH
#define NE   6       // experts
#define NT   3       // tasks
#define TAU  1e-4f   // near-tie rescue threshold on 3rd-vs-4th logit gap

typedef _Float16 f16x8 __attribute__((ext_vector_type(8)));
typedef float    f32x4 __attribute__((ext_vector_type(4)));

// ---------------------------------------------------------------------------
// global -> LDS staging, 16B per lane, wave-uniform base (lane*16 implicit)
// ---------------------------------------------------------------------------
__device__ __forceinline__ void stage16(const _Float16* g, _Float16* lds_base, int lane)
{
#if __has_builtin(__builtin_amdgcn_global_load_lds)
    __builtin_amdgcn_global_load_lds(
        (const __attribute__((address_space(1))) unsigned int*)(uintptr_t)g,
        (__attribute__((address_space(3))) unsigned int*)(uintptr_t)lds_base, 16, 0, 0);
#else
    *(float4*)(lds_base + lane * 8) = *(const float4*)g;
#endif
}

__device__ __forceinline__ f32x4 mfma16(f16x8 a, f16x8 b, f32x4 c)
{
    return __builtin_amdgcn_mfma_f32_16x16x32_f16(a, b, c, 0, 0, 0);
}

// LDS bank-conflict swizzle: row r's k-octet q is stored in LDS slot
// q ^ ((r>>1)&3). Staging achieves this by permuting the GLOBAL source
// octet per lane (LDS dst stays lane-linear, as global_load_lds requires):
// lane (row lr = lane>>2, slot lane&3) fetches global octet (lane&3)^((lr>>1)&3).
// Rows r and r+16 share the swizzle, so both 16-row staging halves agree.
// Fragment readers use slot quad ^ ((fl>>1)&3): 16 fl-lanes then cover all
// 8 (row-parity, slot) combos twice -> uniform 2-way = conflict-free (m136).

// ---------------------------------------------------------------------------
// fp16 MFMA 128x128 tile core. A [rows x DH] fp16, Bt [M x DH] fp16 (pre-T).
// 256 thr = 4 waves 2x2; wave = 64x64 via 4x4 of 16x16x32.
// ---------------------------------------------------------------------------
__device__ __forceinline__ void mfma_tile(const _Float16* __restrict__ A,
                                          const _Float16* __restrict__ Bt,
                                          int n0, int m0, f32x4 acc[4][4])
{
    __shared__ __align__(16) _Float16 As[128 * 32];
    __shared__ __align__(16) _Float16 Bs[128 * 32];
    const int tid  = threadIdx.x;
    const int w    = tid >> 6, lane = tid & 63;
    const int lr   = lane >> 2;
    const int sk   = (((lane & 3) ^ ((lr >> 1) & 3)) * 8);   // swizzled src octet
    const int wm   = (w >> 1) * 64, wn = (w & 1) * 64;
    const int fl   = lane & 15;
    const int fo   = (((lane >> 4) ^ ((fl >> 1) & 3)) * 8);  // swizzled read slot

    const _Float16* ga0 = A  + (size_t)(n0 + w * 32 + lr) * DH + sk;
    const _Float16* ga1 = ga0 + 16 * DH;
    const _Float16* gb0 = Bt + (size_t)(m0 + w * 32 + lr) * DH + sk;
    const _Float16* gb1 = gb0 + 16 * DH;
    _Float16* la0 = As + (w * 32) * 32;
    _Float16* la1 = la0 + 16 * 32;
    _Float16* lb0 = Bs + (w * 32) * 32;
    _Float16* lb1 = lb0 + 16 * 32;

    for (int ks = 0; ks < DH; ks += 32) {
        __syncthreads();
        stage16(ga0 + ks, la0, lane);
        stage16(ga1 + ks, la1, lane);
        stage16(gb0 + ks, lb0, lane);
        stage16(gb1 + ks, lb1, lane);
        __syncthreads();
        f16x8 af[4], bf[4];
#pragma unroll
        for (int i = 0; i < 4; ++i)
            af[i] = *(const f16x8*)(As + (wm + i * 16 + fl) * 32 + fo);
#pragma unroll
        for (int j = 0; j < 4; ++j)
            bf[j] = *(const f16x8*)(Bs + (wn + j * 16 + fl) * 32 + fo);
#pragma unroll
        for (int i = 0; i < 4; ++i)
#pragma unroll
            for (int j = 0; j < 4; ++j)
                acc[i][j] = mfma16(af[i], bf[j], acc[i][j]);
    }
}

// ---------------------------------------------------------------------------
// Split-fp16 (hi+lo) MFMA tile: acc += Ahi*Bhi + Ahi*Blo + Alo*Bhi.
// fp32-accuracy GEMM at MFMA rate (err ~2^-22 rel; np fp32 ref is ~2^-21).
// ---------------------------------------------------------------------------
__device__ __forceinline__ void mfma_tile_split(const _Float16* __restrict__ Ah,
                                                const _Float16* __restrict__ Al,
                                                const _Float16* __restrict__ Bh,
                                                const _Float16* __restrict__ Bl,
                                                int n0, int m0, f32x4 acc[4][4])
{
    __shared__ __align__(16) _Float16 Ash[128 * 32];
    __shared__ __align__(16) _Float16 Asl[128 * 32];
    __shared__ __align__(16) _Float16 Bsh[128 * 32];
    __shared__ __align__(16) _Float16 Bsl[128 * 32];
    const int tid  = threadIdx.x;
    const int w    = tid >> 6, lane = tid & 63;
    const int lr   = lane >> 2;
    const int sk   = (((lane & 3) ^ ((lr >> 1) & 3)) * 8);
    const int wm   = (w >> 1) * 64, wn = (w & 1) * 64;
    const int fl   = lane & 15;
    const int fo   = (((lane >> 4) ^ ((fl >> 1) & 3)) * 8);

    const size_t ro = (size_t)(n0 + w * 32 + lr) * DH + sk;
    const size_t co = (size_t)(m0 + w * 32 + lr) * DH + sk;
    const int lo0 = (w * 32) * 32, lo1 = lo0 + 16 * 32;

    for (int ks = 0; ks < DH; ks += 32) {
        __syncthreads();
        stage16(Ah + ro + ks,            Ash + lo0, lane);
        stage16(Ah + ro + 16 * DH + ks,  Ash + lo1, lane);
        stage16(Al + ro + ks,            Asl + lo0, lane);
        stage16(Al + ro + 16 * DH + ks,  Asl + lo1, lane);
        stage16(Bh + co + ks,            Bsh + lo0, lane);
        stage16(Bh + co + 16 * DH + ks,  Bsh + lo1, lane);
        stage16(Bl + co + ks,            Bsl + lo0, lane);
        stage16(Bl + co + 16 * DH + ks,  Bsl + lo1, lane);
        __syncthreads();
        f16x8 ah[4], al[4], bh[4], bl[4];
#pragma unroll
        for (int i = 0; i < 4; ++i) {
            const int off = (wm + i * 16 + fl) * 32 + fo;
            ah[i] = *(const f16x8*)(Ash + off);
            al[i] = *(const f16x8*)(Asl + off);
        }
#pragma unroll
        for (int j = 0; j < 4; ++j) {
            const int off = (wn + j * 16 + fl) * 32 + fo;
            bh[j] = *(const f16x8*)(Bsh + off);
            bl[j] = *(const f16x8*)(Bsl + off);
        }
#pragma unroll
        for (int i = 0; i < 4; ++i)
#pragma unroll
            for (int j = 0; j < 4; ++j) {
                acc[i][j] = mfma16(al[i], bh[j], acc[i][j]);
                acc[i][j] = mfma16(ah[i], bl[j], acc[i][j]);
                acc[i][j] = mfma16(ah[i], bh[j], acc[i][j]);
            }
    }
}

// C/D layout: col = wn + j*16 + (lane&15); row = wm + i*16 + (lane>>4)*4 + reg.

// ---------------------------------------------------------------------------
// fc1: h1 = relu(x@w1 + b1), output as split fp16 pair (hi, lo)
// ---------------------------------------------------------------------------
__global__ __launch_bounds__(256) void k_fc1(const _Float16* __restrict__ xh,
                                             const _Float16* __restrict__ xl,
                                             const _Float16* __restrict__ wh,
                                             const _Float16* __restrict__ wl,
                                             const float* __restrict__ bias,
                                             _Float16* __restrict__ oh,
                                             _Float16* __restrict__ ol)
{
    f32x4 acc[4][4] = {};
    const int n0 = blockIdx.x * 128, m0 = blockIdx.y * 128;
    mfma_tile_split(xh, xl, wh, wl, n0, m0, acc);
    const int lane = threadIdx.x & 63, w = threadIdx.x >> 6;
    const int wm = (w >> 1) * 64, wn = (w & 1) * 64;
    const int fl = lane & 15, quad = lane >> 4;
#pragma unroll
    for (int i = 0; i < 4; ++i)
#pragma unroll
        for (int reg = 0; reg < 4; ++reg) {
            const int r = n0 + wm + i * 16 + quad * 4 + reg;
#pragma unroll
            for (int j = 0; j < 4; ++j) {
                const int c = m0 + wn + j * 16 + fl;
                const float v = fmaxf(acc[i][j][reg] + bias[c], 0.0f);
                const _Float16 h = (_Float16)v;
                oh[(size_t)r * DH + c] = h;
                ol[(size_t)r * DH + c] = (_Float16)(v - (float)h);
            }
        }
}

// ---------------------------------------------------------------------------
// fc2: h = h1@w2 + b2 -> h32 (fp64 rescue), h16 hi (experts+logits), h16l lo
// ---------------------------------------------------------------------------
__global__ __launch_bounds__(256) void k_fc2(const _Float16* __restrict__ ah,
                                             const _Float16* __restrict__ al,
                                             const _Float16* __restrict__ wh,
                                             const _Float16* __restrict__ wl,
                                             const float* __restrict__ bias,
                                             float* __restrict__ h32,
                                             _Float16* __restrict__ h16,
                                             _Float16* __restrict__ h16l)
{
    f32x4 acc[4][4] = {};
    const int n0 = blockIdx.x * 128, m0 = blockIdx.y * 128;
    mfma_tile_split(ah, al, wh, wl, n0, m0, acc);
    const int lane = threadIdx.x & 63, w = threadIdx.x >> 6;
    const int wm = (w >> 1) * 64, wn = (w & 1) * 64;
    const int fl = lane & 15, quad = lane >> 4;
#pragma unroll
    for (int i = 0; i < 4; ++i)
#pragma unroll
        for (int reg = 0; reg < 4; ++reg) {
            const int r = n0 + wm + i * 16 + quad * 4 + reg;
#pragma unroll
            for (int j = 0; j < 4; ++j) {
                const int c = m0 + wn + j * 16 + fl;
                const float v = acc[i][j][reg] + bias[c];
                const _Float16 h = (_Float16)v;
                h32[(size_t)r * DH + c] = v;
                h16[(size_t)r * DH + c] = h;
                h16l[(size_t)r * DH + c] = (_Float16)(v - (float)h);
            }
        }
}

// ---------------------------------------------------------------------------
// Gating logits via split-fp16 MFMA: logits[c][n] = h[n,:].wg[:,c], c=t*6+e
// (32 cols, 18 real + zero pad). Block = 128 thr = 2 waves, 64 tokens.
// ---------------------------------------------------------------------------
__global__ __launch_bounds__(128) void k_logits(const _Float16* __restrict__ hh,
                                                const _Float16* __restrict__ hl,
                                                const _Float16* __restrict__ wgh, // [32][DH]
                                                const _Float16* __restrict__ wgl,
                                                float* __restrict__ logits,       // [32][chunk]
                                                int chunk)
{
    __shared__ __align__(16) _Float16 Ash[64 * 32];
    __shared__ __align__(16) _Float16 Asl[64 * 32];
    __shared__ __align__(16) _Float16 Bsh[32 * 32];
    __shared__ __align__(16) _Float16 Bsl[32 * 32];
    const int tid = threadIdx.x;
    const int w = tid >> 6, lane = tid & 63;
    const int lr = lane >> 2;
    const int sk = (((lane & 3) ^ ((lr >> 1) & 3)) * 8);
    const int fl = lane & 15;
    const int fo = (((lane >> 4) ^ ((fl >> 1) & 3)) * 8);
    const int n0 = blockIdx.x * 64;

    const size_t ro = (size_t)(n0 + w * 32 + lr) * DH + sk;
    const size_t bo = (size_t)lr * DH + sk;
    const int la0 = (w * 32) * 32, la1 = la0 + 16 * 32;

    f32x4 acc[2][2] = {};
    for (int ks = 0; ks < DH; ks += 32) {
        __syncthreads();
        stage16(hh + ro + ks,           Ash + la0, lane);
        stage16(hh + ro + 16 * DH + ks, Ash + la1, lane);
        stage16(hl + ro + ks,           Asl + la0, lane);
        stage16(hl + ro + 16 * DH + ks, Asl + la1, lane);
        if (w == 0) {
            stage16(wgh + bo + ks,           Bsh,           lane);
            stage16(wgh + bo + 16 * DH + ks, Bsh + 16 * 32, lane);
        } else {
            stage16(wgl + bo + ks,           Bsl,           lane);
            stage16(wgl + bo + 16 * DH + ks, Bsl + 16 * 32, lane);
        }
        __syncthreads();
        f16x8 ah[2], al[2], bh[2], bl[2];
#pragma unroll
        for (int i = 0; i < 2; ++i) {
            const int off = (w * 32 + i * 16 + fl) * 32 + fo;
            ah[i] = *(const f16x8*)(Ash + off);
            al[i] = *(const f16x8*)(Asl + off);
        }
#pragma unroll
        for (int j = 0; j < 2; ++j) {
            const int off = (j * 16 + fl) * 32 + fo;
            bh[j] = *(const f16x8*)(Bsh + off);
            bl[j] = *(const f16x8*)(Bsl + off);
        }
#pragma unroll
        for (int i = 0; i < 2; ++i)
#pragma unroll
            for (int j = 0; j < 2; ++j) {
                acc[i][j] = mfma16(al[i], bh[j], acc[i][j]);
                acc[i][j] = mfma16(ah[i], bl[j], acc[i][j]);
                acc[i][j] = mfma16(ah[i], bh[j], acc[i][j]);
            }
    }
    const int quad = lane >> 4;
#pragma unroll
    for (int i = 0; i < 2; ++i)
#pragma unroll
        for (int reg = 0; reg < 4; ++reg) {
            const int r = n0 + w * 32 + i * 16 + quad * 4 + reg;
#pragma unroll
            for (int j = 0; j < 2; ++j) {
                const int c = j * 16 + fl;
                logits[(size_t)c * chunk + r] = acc[i][j][reg];
            }
        }
}

// ---------------------------------------------------------------------------
// Select: per-token top-3 + fp32 softmax -> gates; flag near-ties (3rd vs 4th)
// ---------------------------------------------------------------------------
__global__ __launch_bounds__(256) void k_select(const float* __restrict__ logits, // [32][chunk]
                                                float* __restrict__ gates,        // [E][T][chunk]
                                                unsigned char* __restrict__ flags,
                                                int chunk)
{
    const int n = blockIdx.x * 256 + threadIdx.x;
    if (n >= chunk) return;
    float l[18];
#pragma unroll
    for (int c = 0; c < 18; ++c) l[c] = logits[(size_t)c * chunk + n];
    unsigned char f = 0;
#pragma unroll
    for (int t = 0; t < NT; ++t) {
        float a[NE];
#pragma unroll
        for (int e = 0; e < NE; ++e) a[e] = l[t * NE + e];
        bool used[NE] = {false, false, false, false, false, false};
        int idx[3];
        float tv[3];
#pragma unroll
        for (int k = 0; k < 3; ++k) {
            int best = -1;
#pragma unroll
            for (int e = 0; e < NE; ++e)
                if (!used[e] && (best < 0 || a[e] > a[best])) best = e;
            used[best] = true;
            idx[k] = best;
            tv[k] = a[best];
        }
        float v4 = -3.4e38f;
#pragma unroll
        for (int e = 0; e < NE; ++e)
            if (!used[e] && a[e] > v4) v4 = a[e];
        if (tv[2] - v4 < TAU) f = 1;
        const float m = tv[0];
        const float w0 = expf(tv[0] - m), w1 = expf(tv[1] - m), w2 = expf(tv[2] - m);
        const float s = w0 + w1 + w2;
        float g[NE] = {0.f, 0.f, 0.f, 0.f, 0.f, 0.f};
        g[idx[0]] = w0 / s;
        g[idx[1]] = w1 / s;
        g[idx[2]] = w2 / s;
#pragma unroll
        for (int e = 0; e < NE; ++e)
            gates[(size_t)(e * NT + t) * chunk + n] = g[e];
    }
    flags[n] = f;
}

// ---------------------------------------------------------------------------
// Rescue: fp64-exact gating for flagged (near-tie) tokens only. Wave-per-token.
// ---------------------------------------------------------------------------
__global__ __launch_bounds__(256) void k_rescue(const float* __restrict__ h,    // [chunk][DH]
                                                const double* __restrict__ wgt, // [T][E][DH]
                                                const unsigned char* __restrict__ flags,
                                                float* __restrict__ gates,      // [E][T][chunk]
                                                int chunk)
{
    const int w = threadIdx.x >> 6, lane = threadIdx.x & 63;
    const int n = blockIdx.x * 4 + w;
    if (!flags[n]) return;   // wave-uniform early out

    double acc[NT][NE] = {};
#pragma unroll 4
    for (int i = 0; i < 16; ++i) {
        const int k = lane + 64 * i;
        const double hv = (double)h[(size_t)n * DH + k];
#pragma unroll
        for (int t = 0; t < NT; ++t)
#pragma unroll
            for (int e = 0; e < NE; ++e)
                acc[t][e] += hv * wgt[(size_t)(t * NE + e) * DH + k];
    }
#pragma unroll
    for (int d = 1; d < 64; d <<= 1)
#pragma unroll
        for (int t = 0; t < NT; ++t)
#pragma unroll
            for (int e = 0; e < NE; ++e)
                acc[t][e] += __shfl_xor(acc[t][e], d, 64);

    if (lane < NT) {
        const int t = lane;
        double a[NE];
#pragma unroll
        for (int e = 0; e < NE; ++e) a[e] = acc[t][e];
        bool used[NE] = {false, false, false, false, false, false};
        int idx[3];
        double tv[3];
#pragma unroll
        for (int k = 0; k < 3; ++k) {
            int best = -1;
#pragma unroll
            for (int e = 0; e < NE; ++e)
                if (!used[e] && (best < 0 || a[e] > a[best])) best = e;
            used[best] = true;
            idx[k] = best;
            tv[k] = a[best];
        }
        const double m  = tv[0];
        const double w0 = exp(tv[0] - m), w1 = exp(tv[1] - m), w2 = exp(tv[2] - m);
        const double sum = w0 + w1 + w2;
        float g[NE] = {0.f, 0.f, 0.f, 0.f, 0.f, 0.f};
        g[idx[0]] = (float)(w0 / sum);
        g[idx[1]] = (float)(w1 / sum);
        g[idx[2]] = (float)(w2 / sum);
#pragma unroll
        for (int e = 0; e < NE; ++e)
            gates[(size_t)(e * NT + t) * chunk + n] = g[e];
    }
}

// ---------------------------------------------------------------------------
// Expert layer 1, all experts (z = e): eh[e] = fp16(relu(h16 @ ew1t[e]^T + eb1[e]))
// ---------------------------------------------------------------------------
__global__ __launch_bounds__(256) void k_expert1(const _Float16* __restrict__ A,
                                                 const _Float16* __restrict__ ew1t,
                                                 const float* __restrict__ eb1,
                                                 _Float16* __restrict__ eh,
                                                 int chunk)
{
    const int e = blockIdx.z;
    const _Float16* Bt = ew1t + (size_t)e * DH * DH;
    const float* bias  = eb1 + e * DH;
    _Float16* C        = eh + (size_t)e * chunk * DH;

    f32x4 acc[4][4] = {};
    const int n0 = blockIdx.x * 128, m0 = blockIdx.y * 128;
    mfma_tile(A, Bt, n0, m0, acc);
    const int lane = threadIdx.x & 63, w = threadIdx.x >> 6;
    const int wm = (w >> 1) * 64, wn = (w & 1) * 64;
    const int fl = lane & 15, quad = lane >> 4;
#pragma unroll
    for (int i = 0; i < 4; ++i)
#pragma unroll
        for (int reg = 0; reg < 4; ++reg) {
            const int r = n0 + wm + i * 16 + quad * 4 + reg;
#pragma unroll
            for (int j = 0; j < 4; ++j) {
                const int c = m0 + wn + j * 16 + fl;
                C[(size_t)r * DH + c] = (_Float16)fmaxf(acc[i][j][reg] + bias[c], 0.0f);
            }
        }
}

// ---------------------------------------------------------------------------
// Expert layer 2, all experts (z = e): eo[e] = fp16(eh[e] @ ew2t[e]^T + eb2[e])
// ---------------------------------------------------------------------------
__global__ __launch_bounds__(256) void k_expert2(const _Float16* __restrict__ eh,
                                                 const _Float16* __restrict__ ew2t,
                                                 const float* __restrict__ eb2,
                                                 _Float16* __restrict__ eo,
                                                 int chunk)
{
    const int e = blockIdx.z;
    const _Float16* A  = eh + (size_t)e * chunk * DH;
    const _Float16* Bt = ew2t + (size_t)e * DH * DH;
    const float* bias  = eb2 + e * DH;
    _Float16* C        = eo + (size_t)e * chunk * DH;

    f32x4 acc[4][4] = {};
    const int n0 = blockIdx.x * 128, m0 = blockIdx.y * 128;
    mfma_tile(A, Bt, n0, m0, acc);
    const int lane = threadIdx.x & 63, w = threadIdx.x >> 6;
    const int wm = (w >> 1) * 64, wn = (w & 1) * 64;
    const int fl = lane & 15, quad = lane >> 4;
#pragma unroll
    for (int i = 0; i < 4; ++i)
#pragma unroll
        for (int reg = 0; reg < 4; ++reg) {
            const int r = n0 + wm + i * 16 + quad * 4 + reg;
#pragma unroll
            for (int j = 0; j < 4; ++j) {
                const int c = m0 + wn + j * 16 + fl;
                C[(size_t)r * DH + c] = (_Float16)(acc[i][j][reg] + bias[c]);
            }
        }
}

// ---------------------------------------------------------------------------
// Gated combine: mo[t][n][:] = sum_e gates[e][t][n] * eo[e][n][:]
// ---------------------------------------------------------------------------
__global__ __launch_bounds__(256) void k_combine(const _Float16* __restrict__ eo,
                                                 const float* __restrict__ gates, // [E][T][chunk]
                                                 _Float16* __restrict__ mo,       // [T][chunk][DH]
                                                 int chunk)
{
    const size_t plane = (size_t)chunk * DH;
    const size_t idx = (size_t)blockIdx.x * 256 + threadIdx.x;
    const size_t off = idx * 8;
    if (off >= plane) return;
    const int n = (int)(off / DH);

    float acc[NT][8] = {};
#pragma unroll
    for (int e = 0; e < NE; ++e) {
        const f16x8 v = *(const f16x8*)(eo + e * plane + off);
        float vf[8];
#pragma unroll
        for (int j = 0; j < 8; ++j) vf[j] = (float)v[j];
#pragma unroll
        for (int t = 0; t < NT; ++t) {
            const float g = gates[(size_t)(e * NT + t) * chunk + n];
#pragma unroll
            for (int j = 0; j < 8; ++j) acc[t][j] += g * vf[j];
        }
    }
#pragma unroll
    for (int t = 0; t < NT; ++t) {
        f16x8 r;
#pragma unroll
        for (int j = 0; j < 8; ++j) r[j] = (_Float16)acc[t][j];
        *(f16x8*)(mo + t * plane + off) = r;
    }
}

// ---------------------------------------------------------------------------
// Tower: th = relu(mo[t]@tw1t[t]^T + tb1[t]); out[t][n] += th . tw2[t]
// ---------------------------------------------------------------------------
__global__ __launch_bounds__(256) void k_mfma_tower(const _Float16* __restrict__ mo,
                                                    const _Float16* __restrict__ tw1t,
                                                    const float* __restrict__ tb1,
                                                    const float* __restrict__ tw2,
                                                    float* __restrict__ out,
                                                    int n_base, int chunk)
{
    const int t = blockIdx.z;
    const _Float16* A  = mo   + (size_t)t * chunk * DH;
    const _Float16* Bt = tw1t + (size_t)t * DH * DH;
    const float* b1 = tb1 + t * DH;
    const float* w2 = tw2 + t * DH;

    f32x4 acc[4][4] = {};
    const int n0 = blockIdx.x * 128, m0 = blockIdx.y * 128;
    mfma_tile(A, Bt, n0, m0, acc);
    const int lane = threadIdx.x & 63, w = threadIdx.x >> 6;
    const int wm = (w >> 1) * 64, wn = (w & 1) * 64;
    const int fl = lane & 15, quad = lane >> 4;

    float s[4][4];
#pragma unroll
    for (int i = 0; i < 4; ++i)
#pragma unroll
        for (int reg = 0; reg < 4; ++reg) {
            float v = 0.0f;
#pragma unroll
            for (int j = 0; j < 4; ++j) {
                const int c = m0 + wn + j * 16 + fl;
                v += fmaxf(acc[i][j][reg] + b1[c], 0.0f) * w2[c];
            }
            s[i][reg] = v;
        }
#pragma unroll
    for (int d = 8; d > 0; d >>= 1)
#pragma unroll
        for (int i = 0; i < 4; ++i)
#pragma unroll
            for (int reg = 0; reg < 4; ++reg)
                s[i][reg] += __shfl_down(s[i][reg], d, 16);
    if (fl == 0) {
#pragma unroll
        for (int i = 0; i < 4; ++i)
#pragma unroll
            for (int reg = 0; reg < 4; ++reg) {
                const int r = n0 + wm + i * 16 + quad * 4 + reg;
                atomicAdd(out + (size_t)t * NTOK + n_base + r, s[i][reg]);
            }
    }
}

// ---------------------------------------------------------------------------
// Utility kernels
// ---------------------------------------------------------------------------
__global__ __launch_bounds__(256) void k_init_out(float* __restrict__ out,
                                                  const float* __restrict__ tb2)
{
    const int i = blockIdx.x * 256 + threadIdx.x;
    if (i < NT * NTOK) out[i] = tb2[i >> 14];
}

// vectorized split fp32 -> (hi, lo) fp16, 8 elems/thread
__global__ __launch_bounds__(256) void k_xsplit8(const float* __restrict__ s,
                                                 _Float16* __restrict__ hi,
                                                 _Float16* __restrict__ lo, size_t n8)
{
    const size_t i = (size_t)blockIdx.x * 256 + threadIdx.x;
    if (i >= n8) return;
    const size_t off = i * 8;
    const float4 a = *(const float4*)(s + off);
    const float4 b = *(const float4*)(s + off + 4);
    const float v[8] = {a.x, a.y, a.z, a.w, b.x, b.y, b.z, b.w};
    f16x8 H, L;
#pragma unroll
    for (int j = 0; j < 8; ++j) {
        const _Float16 h = (_Float16)v[j];
        H[j] = h;
        L[j] = (_Float16)(v[j] - (float)h);
    }
    *(f16x8*)(hi + off) = H;
    *(f16x8*)(lo + off) = L;
}

// transpose one DH x DH fp32 [K][M] -> fp16 [M][K]; matrix index blockIdx.z
__global__ __launch_bounds__(256) void k_w16t(const float* __restrict__ src,
                                              _Float16* __restrict__ dst)
{
    __shared__ float t[32][33];
    const float* s = src + (size_t)blockIdx.z * DH * DH;
    _Float16* d    = dst + (size_t)blockIdx.z * DH * DH;
    const int k0 = blockIdx.x * 32, m0 = blockIdx.y * 32;
    const int tx = threadIdx.x & 31, ty = threadIdx.x >> 5;
    for (int r = ty; r < 32; r += 8)
        t[r][tx] = s[(size_t)(k0 + r) * DH + m0 + tx];
    __syncthreads();
    for (int r = ty; r < 32; r += 8)
        d[(size_t)(m0 + r) * DH + k0 + tx] = (_Float16)t[tx][r];
}

// transpose + split one DH x DH fp32 [K][M] -> fp16 hi/lo [M][K]
__global__ __launch_bounds__(256) void k_wsplit_t(const float* __restrict__ src,
                                                  _Float16* __restrict__ dhi,
                                                  _Float16* __restrict__ dlo)
{
    __shared__ float t[32][33];
    const int k0 = blockIdx.x * 32, m0 = blockIdx.y * 32;
    const int tx = threadIdx.x & 31, ty = threadIdx.x >> 5;
    for (int r = ty; r < 32; r += 8)
        t[r][tx] = src[(size_t)(k0 + r) * DH + m0 + tx];
    __syncthreads();
    for (int r = ty; r < 32; r += 8) {
        const float v = t[tx][r];
        const _Float16 h = (_Float16)v;
        dhi[(size_t)(m0 + r) * DH + k0 + tx] = h;
        dlo[(size_t)(m0 + r) * DH + k0 + tx] = (_Float16)(v - (float)h);
    }
}

// w_gate [T][DH][E] fp32 -> wgt [T][E][DH] fp64 (rescue path)
__global__ __launch_bounds__(256) void k_wg_t(const float* __restrict__ wg,
                                              double* __restrict__ wgt)
{
    const int i = blockIdx.x * 256 + threadIdx.x;
    if (i < NT * NE * DH) {
        const int k = i & (DH - 1);
        const int te = i >> 10;
        const int e = te % NE, t = te / NE;
        wgt[i] = (double)wg[((size_t)t * DH + k) * NE + e];
    }
}

// w_gate [T][DH][E] fp32 -> split fp16 [32][DH] (c = t*6+e, rows 18..31 zero)
__global__ __launch_bounds__(256) void k_wgsplit(const float* __restrict__ wg,
                                                 _Float16* __restrict__ wgh,
                                                 _Float16* __restrict__ wgl)
{
    const int i = blockIdx.x * 256 + threadIdx.x;
    if (i >= 32 * DH) return;
    const int k = i & (DH - 1);
    const int c = i >> 10;
    float v = 0.0f;
    if (c < NT * NE) {
        const int t = c / NE, e = c - t * NE;
        v = wg[((size_t)t * DH + k) * NE + e];
    }
    const _Float16 h = (_Float16)v;
    wgh[i] = h;
    wgl[i] = (_Float16)(v - (float)h);
}

// ---------------------------------------------------------------------------
extern "C" void kernel_launch(void* const* d_in, const int* in_sizes, int n_in,
                              void* d_out, int out_size, void* d_ws, size_t ws_size,
                              hipStream_t stream)
{
    const float* x      = (const float*)d_in[0];
    const float* fc1_w  = (const float*)d_in[1];
    const float* fc1_b  = (const float*)d_in[2];
    const float* fc2_w  = (const float*)d_in[3];
    const float* fc2_b  = (const float*)d_in[4];
    const float* w_gate = (const float*)d_in[5];
    const float* ew1    = (const float*)d_in[6];
    const float* eb1    = (const float*)d_in[7];
    const float* ew2    = (const float*)d_in[8];
    const float* eb2    = (const float*)d_in[9];
    const float* tw1    = (const float*)d_in[10];
    const float* tb1    = (const float*)d_in[11];
    const float* tw2    = (const float*)d_in[12];
    const float* tb2    = (const float*)d_in[13];
    float* out = (float*)d_out;

    const size_t plane = (size_t)DH * DH * 2;           // 2 MiB
    // fixed: 19 fp16 weight planes + wgt fp64 + wgh/wgl fp16
    const size_t fixed = 19 * plane + (size_t)NT * NE * DH * 8 + (size_t)2 * 32 * DH * 2;
    // per-token: eh(6) + h16(1) + eo(6) fp16 planes + gates + flags
    // (h16l and logits alias into eo planes 1 / 0 — dead before expert2 writes)
    const size_t per_tok = (size_t)13 * DH * 2 + NE * NT * 4 + 1;
    int chunk = 16384;
    while (chunk > 128 && fixed + (size_t)chunk * per_tok > ws_size) chunk >>= 1;

    char* p = (char*)d_ws;
    _Float16* ew1t = (_Float16*)p; p += NE * plane;
    _Float16* ew2t = (_Float16*)p; p += NE * plane;
    _Float16* tw1t = (_Float16*)p; p += NT * plane;
    _Float16* w1th = (_Float16*)p; p += plane;
    _Float16* w1tl = (_Float16*)p; p += plane;
    _Float16* w2th = (_Float16*)p; p += plane;
    _Float16* w2tl = (_Float16*)p; p += plane;
    double* wgt    = (double*)p;   p += (size_t)NT * NE * DH * 8;
    _Float16* wgh  = (_Float16*)p; p += (size_t)32 * DH * 2;
    _Float16* wgl  = (_Float16*)p; p += (size_t)32 * DH * 2;

    const size_t cpe = (size_t)chunk * DH;     // chunk-plane elements
    _Float16* eh   = (_Float16*)p; p += 6 * cpe * 2;
    _Float16* h16  = (_Float16*)p; p += cpe * 2;
    _Float16* eo   = (_Float16*)p; p += 6 * cpe * 2;
    float* gates   = (float*)p;    p += (size_t)NE * NT * chunk * 4;
    unsigned char* flags = (unsigned char*)p; p += chunk;

    // aliases inside eh (lifetimes end before eh is written by k_expert1)
    _Float16* xh  = eh + 0 * cpe;
    _Float16* xl  = eh + 1 * cpe;
    _Float16* h1h = eh + 2 * cpe;
    _Float16* h1l = eh + 3 * cpe;
    float*    h32 = (float*)(eh + 4 * cpe);    // planes 4-5
    _Float16* mo  = eh;                        // 3 planes, after eh dead
    // aliases inside eo (lifetimes end before eo is written by k_expert2)
    float* logits  = (float*)eo;               // 32*chunk*4 B in plane 0
    _Float16* h16l = eo + 1 * cpe;             // plane 1

    const dim3 blk(256);
    const dim3 gm(chunk / 128, DH / 128);
    const dim3 gme(chunk / 128, DH / 128, NE);

    k_init_out<<<dim3((NT * NTOK + 255) / 256), blk, 0, stream>>>(out, tb2);

    // one-time weight prep
    k_w16t<<<dim3(32, 32, NE), blk, 0, stream>>>(ew1, ew1t);
    k_w16t<<<dim3(32, 32, NE), blk, 0, stream>>>(ew2, ew2t);
    k_w16t<<<dim3(32, 32, NT), blk, 0, stream>>>(tw1, tw1t);
    k_wsplit_t<<<dim3(32, 32), blk, 0, stream>>>(fc1_w, w1th, w1tl);
    k_wsplit_t<<<dim3(32, 32), blk, 0, stream>>>(fc2_w, w2th, w2tl);
    k_wg_t<<<dim3((NT * NE * DH + 255) / 256), blk, 0, stream>>>(w_gate, wgt);
    k_wgsplit<<<dim3((32 * DH + 255) / 256), blk, 0, stream>>>(w_gate, wgh, wgl);

    for (int nb = 0; nb < NTOK; nb += chunk) {
        const float* xc = x + (size_t)nb * DH;

        // shared bottom via split-fp16 MFMA (fp32-accurate -> selection-safe)
        k_xsplit8<<<dim3((unsigned)((cpe / 8 + 255) / 256)), blk, 0, stream>>>(xc, xh, xl, cpe / 8);
        k_fc1<<<gm, blk, 0, stream>>>(xh, xl, w1th, w1tl, fc1_b, h1h, h1l);
        k_fc2<<<gm, blk, 0, stream>>>(h1h, h1l, w2th, w2tl, fc2_b, h32, h16, h16l);

        // gating: MFMA logits + fp32 select + fp64 rescue of near-ties
        k_logits<<<dim3(chunk / 64), dim3(128), 0, stream>>>(h16, h16l, wgh, wgl, logits, chunk);
        k_select<<<dim3(chunk / 256), blk, 0, stream>>>(logits, gates, flags, chunk);
        k_rescue<<<dim3(chunk / 4), blk, 0, stream>>>(h32, wgt, flags, gates, chunk);

        // experts: both layers fully parallel over e
        k_expert1<<<gme, blk, 0, stream>>>(h16, ew1t, eb1, eh, chunk);
        k_expert2<<<gme, blk, 0, stream>>>(eh, ew2t, eb2, eo, chunk);

        // gated combine (elementwise) -> mo (reuses eh planes 0-2)
        k_combine<<<dim3((unsigned)((cpe / 8 + 255) / 256)), blk, 0, stream>>>(
            eo, gates, mo, chunk);

        // towers via fp16 MFMA + fused final dot
        k_mfma_tower<<<dim3(chunk / 128, DH / 128, NT), blk, 0, stream>>>(
            mo, tw1t, tb1, tw2, out, nb, chunk);
    }
}